// Round 1
// baseline (256.854 us; speedup 1.0000x reference)
//
#include <hip/hip_runtime.h>
#include <math.h>

#define NN 512     // N_NODES
#define SD 32      // STATE_DIM == MESSAGE_DIM
#define HM 64      // H_MSG

typedef __bf16 bf16x8 __attribute__((ext_vector_type(8)));
typedef float floatx4 __attribute__((ext_vector_type(4)));

__device__ __forceinline__ float sigmoidf_(float x) {
    return 1.0f / (1.0f + __expf(-x));
}

// ---------------------------------------------------------------------------
// Kernel A: node projections
//   hip[i][c] = sum_d h[i][d]*W1[c][d]      + b[i]*W1[c][65]
//   hjp[j][c] = sum_d h[j][d]*W1[c][32+d]   + b[j]*W1[c][66] + mp_b1[c]
// mp_W1 is (64, 67) row-major.
// ---------------------------------------------------------------------------
__global__ __launch_bounds__(256) void node_proj_kernel(
    const float* __restrict__ h, const float* __restrict__ b,
    const float* __restrict__ mpW1, const float* __restrict__ mpb1,
    float* __restrict__ hip_, float* __restrict__ hjp_, int hzero)
{
    int id = blockIdx.x * blockDim.x + threadIdx.x;   // 512*64
    if (id >= NN * HM) return;
    int i = id >> 6, c = id & 63;
    const float* w = mpW1 + c * 67;
    float bi = b[i];
    float si = bi * w[65];
    float sj = bi * w[66] + mpb1[c];
    if (!hzero) {
        const float* hr = h + i * SD;
        #pragma unroll
        for (int d = 0; d < SD; ++d) {
            float hv = hr[d];
            si = fmaf(hv, w[d], si);
            sj = fmaf(hv, w[32 + d], sj);
        }
    }
    hip_[id] = si;
    hjp_[id] = sj;
}

// ---------------------------------------------------------------------------
// Kernel B: fused edge MLP + column-sum.  One block per j (512 blocks),
// 4 waves; wave w covers i in [w*128, w*128+128) in 8 groups of 16 edges.
// Per group: m1 (16x64 bf16, A-layout in regs) -> MFMA GEMM1 (x8) ->
// bias/relu -> LDS -> A-layout reload -> MFMA GEMM2 (x4) -> bias/relu ->
// fp32 accumulate.  End: row-sum + shfl reduce + cross-wave LDS reduce ->
// msg_sum[j][0..31].
// ---------------------------------------------------------------------------
__global__ __launch_bounds__(256, 2) void edge_mlp_kernel(
    const float* __restrict__ hip_, const float* __restrict__ hjp_,
    const float* __restrict__ J, const float* __restrict__ mpW1,
    const float* __restrict__ mpW2, const float* __restrict__ mpb2,
    const float* __restrict__ mpW3, const float* __restrict__ mpb3,
    float* __restrict__ msg_sum)
{
    __shared__ __align__(16) __bf16 m2s[4][16][72];  // per-wave 16 edges x 64 ch (+8 pad)
    __shared__ float msum[4][32];

    const int j    = blockIdx.x;
    const int lane = threadIdx.x & 63;
    const int wave = threadIdx.x >> 6;
    const int q    = lane >> 4;     // k-quad
    const int c    = lane & 15;     // A-row / C-col index

    // ---- per-wave preloads ----
    float hjp_r[16], wj_r[16];
    #pragma unroll
    for (int s = 0; s < 8; ++s) {
        int k0 = q * 8 + s;
        hjp_r[s]     = hjp_[j * 64 + k0];
        hjp_r[8 + s] = hjp_[j * 64 + k0 + 32];
        wj_r[s]      = mpW1[k0 * 67 + 64];
        wj_r[8 + s]  = mpW1[(k0 + 32) * 67 + 64];
    }
    float b2v[4], b3v[2];
    #pragma unroll
    for (int t = 0; t < 4; ++t) b2v[t] = mpb2[t * 16 + c];
    #pragma unroll
    for (int t = 0; t < 2; ++t) b3v[t] = mpb3[t * 16 + c];

    // W2 as B-operand frags: B[k][n] = W2[n][k]; element s -> W2[(t*16+c)][f*32+q*8+s]
    bf16x8 Bw2[2][4];
    #pragma unroll
    for (int f = 0; f < 2; ++f)
        #pragma unroll
        for (int t = 0; t < 4; ++t) {
            const float* src = mpW2 + (t * 16 + c) * 64 + f * 32 + q * 8;
            bf16x8 v;
            #pragma unroll
            for (int s = 0; s < 8; ++s) v[s] = (__bf16)src[s];
            Bw2[f][t] = v;
        }
    // W3 (32x64) likewise
    bf16x8 Bw3[2][2];
    #pragma unroll
    for (int f = 0; f < 2; ++f)
        #pragma unroll
        for (int t = 0; t < 2; ++t) {
            const float* src = mpW3 + (t * 16 + c) * 64 + f * 32 + q * 8;
            bf16x8 v;
            #pragma unroll
            for (int s = 0; s < 8; ++s) v[s] = (__bf16)src[s];
            Bw3[f][t] = v;
        }

    float accf[2][4];
    #pragma unroll
    for (int t = 0; t < 2; ++t)
        #pragma unroll
        for (int r = 0; r < 4; ++r) accf[t][r] = 0.0f;

    const floatx4 zero4 = {0.f, 0.f, 0.f, 0.f};

    for (int g = 0; g < 8; ++g) {
        const int row = wave * 128 + g * 16 + c;       // source node i (A-row m = c)
        const float4* hp = (const float4*)(hip_ + row * 64);
        float4 h0 = hp[q * 2];
        float4 h1 = hp[q * 2 + 1];
        float4 h2 = hp[q * 2 + 8];
        float4 h3 = hp[q * 2 + 9];
        float Jv = J[row * NN + j];

        float va[16];
        va[0] = h0.x; va[1] = h0.y; va[2]  = h0.z; va[3]  = h0.w;
        va[4] = h1.x; va[5] = h1.y; va[6]  = h1.z; va[7]  = h1.w;
        va[8] = h2.x; va[9] = h2.y; va[10] = h2.z; va[11] = h2.w;
        va[12] = h3.x; va[13] = h3.y; va[14] = h3.z; va[15] = h3.w;

        bf16x8 a0, a1;
        #pragma unroll
        for (int s = 0; s < 8; ++s) {
            float v0 = fmaf(Jv, wj_r[s],     va[s]     + hjp_r[s]);
            float v1 = fmaf(Jv, wj_r[8 + s], va[8 + s] + hjp_r[8 + s]);
            a0[s] = (__bf16)fmaxf(v0, 0.0f);
            a1[s] = (__bf16)fmaxf(v1, 0.0f);
        }

        // GEMM1: m2_pre (16 edges x 64 ch), C layout: row=q*4+r (edge), col=t*16+c (ch)
        floatx4 c1[4];
        #pragma unroll
        for (int t = 0; t < 4; ++t) {
            c1[t] = __builtin_amdgcn_mfma_f32_16x16x32_bf16(a0, Bw2[0][t], zero4, 0, 0, 0);
            c1[t] = __builtin_amdgcn_mfma_f32_16x16x32_bf16(a1, Bw2[1][t], c1[t], 0, 0, 0);
        }

        __syncthreads();  // WAR: prior iteration's reads of m2s are done
        #pragma unroll
        for (int t = 0; t < 4; ++t)
            #pragma unroll
            for (int r = 0; r < 4; ++r) {
                float v = fmaxf(c1[t][r] + b2v[t], 0.0f);
                m2s[wave][q * 4 + r][t * 16 + c] = (__bf16)v;
            }
        __syncthreads();  // RAW: writes visible before A-layout reload

        bf16x8 a2 = *(const bf16x8*)&m2s[wave][c][q * 8];
        bf16x8 a3 = *(const bf16x8*)&m2s[wave][c][q * 8 + 32];

        // GEMM2: msg_pre (16 edges x 32 ch)
        floatx4 c2[2];
        #pragma unroll
        for (int t = 0; t < 2; ++t) {
            c2[t] = __builtin_amdgcn_mfma_f32_16x16x32_bf16(a2, Bw3[0][t], zero4, 0, 0, 0);
            c2[t] = __builtin_amdgcn_mfma_f32_16x16x32_bf16(a3, Bw3[1][t], c2[t], 0, 0, 0);
        }
        #pragma unroll
        for (int t = 0; t < 2; ++t)
            #pragma unroll
            for (int r = 0; r < 4; ++r)
                accf[t][r] += fmaxf(c2[t][r] + b3v[t], 0.0f);
    }

    // column sums: each lane sums its 4 rows, then fold q-groups
    float s0 = accf[0][0] + accf[0][1] + accf[0][2] + accf[0][3];
    float s1 = accf[1][0] + accf[1][1] + accf[1][2] + accf[1][3];
    s0 += __shfl_xor(s0, 16); s0 += __shfl_xor(s0, 32);
    s1 += __shfl_xor(s1, 16); s1 += __shfl_xor(s1, 32);
    if (lane < 16) {
        msum[wave][c]      = s0;
        msum[wave][16 + c] = s1;
    }
    __syncthreads();
    if (threadIdx.x < 32) {
        float tot = msum[0][threadIdx.x] + msum[1][threadIdx.x] +
                    msum[2][threadIdx.x] + msum[3][threadIdx.x];
        msg_sum[j * 32 + threadIdx.x] = tot;
    }
}

// ---------------------------------------------------------------------------
// Kernel C: GRU update. 1 thread per (node, dim). h double-buffered.
// gru_Wih (96,64), gru_Whh (96,32), row-major.
// ---------------------------------------------------------------------------
__global__ __launch_bounds__(256) void gru_kernel(
    const float* __restrict__ h, const float* __restrict__ msg,
    const float* __restrict__ Wih, const float* __restrict__ Whh,
    const float* __restrict__ bih, const float* __restrict__ bhh,
    float* __restrict__ hnew)
{
    int id = blockIdx.x * blockDim.x + threadIdx.x;   // 512*32
    if (id >= NN * SD) return;
    int n = id >> 5, d = id & 31;
    const float* hr = h + n * SD;
    const float* mr = msg + n * SD;
    float gi[3], gh[3];
    #pragma unroll
    for (int g = 0; g < 3; ++g) {
        const float* wi = Wih + (g * 32 + d) * 64;
        const float* wh = Whh + (g * 32 + d) * 32;
        float a  = bih[g * 32 + d];
        float bb = bhh[g * 32 + d];
        #pragma unroll
        for (int k = 0; k < 32; ++k) {
            float hv = hr[k];
            a  = fmaf(hv, wi[k], a);
            a  = fmaf(mr[k], wi[32 + k], a);
            bb = fmaf(hv, wh[k], bb);
        }
        gi[g] = a; gh[g] = bb;
    }
    float r  = sigmoidf_(gi[0] + gh[0]);
    float z  = sigmoidf_(gi[1] + gh[1]);
    float ng = tanhf(gi[2] + r * gh[2]);
    hnew[id] = (1.0f - z) * ng + z * hr[d];
}

// ---------------------------------------------------------------------------
// Kernel D: readout. One wave per node; shuffle-broadcast matvecs.
// r_W1 (64,32), r_W2 (64,64), r_W3 (2,64).
// ---------------------------------------------------------------------------
__global__ __launch_bounds__(256) void readout_kernel(
    const float* __restrict__ h,
    const float* __restrict__ rW1, const float* __restrict__ rb1,
    const float* __restrict__ rW2, const float* __restrict__ rb2,
    const float* __restrict__ rW3, const float* __restrict__ rb3,
    float* __restrict__ out)
{
    int lane = threadIdx.x & 63;
    int wave = threadIdx.x >> 6;
    int n = blockIdx.x * 4 + wave;
    if (n >= NN) return;
    const float* hr = h + n * SD;
    float y1 = rb1[lane];
    #pragma unroll
    for (int k = 0; k < 32; ++k) y1 = fmaf(hr[k], rW1[lane * 32 + k], y1);
    y1 = fmaxf(y1, 0.0f);
    float y2 = rb2[lane];
    #pragma unroll
    for (int k = 0; k < 64; ++k) y2 = fmaf(__shfl(y1, k), rW2[lane * 64 + k], y2);
    y2 = fmaxf(y2, 0.0f);
    float y3 = (lane < 2) ? rb3[lane] : 0.0f;
    #pragma unroll
    for (int k = 0; k < 64; ++k) {
        float v = __shfl(y2, k);
        if (lane < 2) y3 = fmaf(v, rW3[lane * 64 + k], y3);
    }
    if (lane < 2) out[n * 2 + lane] = sigmoidf_(y3);
}

// ---------------------------------------------------------------------------
extern "C" void kernel_launch(void* const* d_in, const int* in_sizes, int n_in,
                              void* d_out, int out_size, void* d_ws, size_t ws_size,
                              hipStream_t stream)
{
    const float* J    = (const float*)d_in[0];
    const float* b    = (const float*)d_in[1];
    const float* mpW1 = (const float*)d_in[2];
    const float* mpb1 = (const float*)d_in[3];
    const float* mpW2 = (const float*)d_in[4];
    const float* mpb2 = (const float*)d_in[5];
    const float* mpW3 = (const float*)d_in[6];
    const float* mpb3 = (const float*)d_in[7];
    const float* Wih  = (const float*)d_in[8];
    const float* Whh  = (const float*)d_in[9];
    const float* bih  = (const float*)d_in[10];
    const float* bhh  = (const float*)d_in[11];
    const float* rW1  = (const float*)d_in[12];
    const float* rb1  = (const float*)d_in[13];
    const float* rW2  = (const float*)d_in[14];
    const float* rb2  = (const float*)d_in[15];
    const float* rW3  = (const float*)d_in[16];
    const float* rb3  = (const float*)d_in[17];

    float* ws   = (float*)d_ws;
    float* h0   = ws;                  // 512*32
    float* h1   = ws + 16384;          // 512*32
    float* hipA = ws + 32768;          // 512*64
    float* hjpA = ws + 65536;          // 512*64
    float* msg  = ws + 98304;          // 512*32

    hipMemsetAsync(h0, 0, NN * SD * sizeof(float), stream);

    float* hc = h0;
    float* hn = h1;
    for (int t = 0; t < 5; ++t) {
        node_proj_kernel<<<128, 256, 0, stream>>>(hc, b, mpW1, mpb1, hipA, hjpA, t == 0);
        edge_mlp_kernel<<<NN, 256, 0, stream>>>(hipA, hjpA, J, mpW1, mpW2, mpb2,
                                                mpW3, mpb3, msg);
        gru_kernel<<<64, 256, 0, stream>>>(hc, msg, Wih, Whh, bih, bhh, hn);
        float* tmp = hn; hn = hc; hc = tmp;
    }
    readout_kernel<<<128, 256, 0, stream>>>(hc, rW1, rb1, rW2, rb2, rW3, rb3,
                                            (float*)d_out);
}

// Round 2
// 206.713 us; speedup vs baseline: 1.2426x; 1.2426x over previous
//
#include <hip/hip_runtime.h>
#include <math.h>

#define NN 512     // N_NODES
#define SD 32      // STATE_DIM == MESSAGE_DIM
#define HM 64      // H_MSG

typedef __bf16 bf16x8 __attribute__((ext_vector_type(8)));
typedef float floatx4 __attribute__((ext_vector_type(4)));

__device__ __forceinline__ float sigmoidf_(float x) {
    return 1.0f / (1.0f + __expf(-x));
}

// ---------------------------------------------------------------------------
// Prep kernel (runs once): JT = J^T ; W2,W3 -> bf16 ; wJ column -> contiguous.
// 256 blocks x 256 threads. Block 0 additionally converts weights.
// ---------------------------------------------------------------------------
__global__ __launch_bounds__(256) void prep_kernel(
    const float* __restrict__ J, float* __restrict__ JT,
    const float* __restrict__ W2, const float* __restrict__ W3,
    const float* __restrict__ mpW1,
    __bf16* __restrict__ w2b, __bf16* __restrict__ w3b,
    float* __restrict__ wjc)
{
    __shared__ float tile[32][33];
    int bx = blockIdx.x & 15, by = blockIdx.x >> 4;
    int tx = threadIdx.x & 31, ty = threadIdx.x >> 5;   // tx 0..31, ty 0..7
    #pragma unroll
    for (int r = 0; r < 32; r += 8)
        tile[ty + r][tx] = J[(by * 32 + ty + r) * NN + bx * 32 + tx];
    __syncthreads();
    #pragma unroll
    for (int r = 0; r < 32; r += 8)
        JT[(bx * 32 + ty + r) * NN + by * 32 + tx] = tile[tx][ty + r];

    if (blockIdx.x == 0) {
        for (int i = threadIdx.x; i < HM * HM; i += 256) w2b[i] = (__bf16)W2[i];
        for (int i = threadIdx.x; i < SD * HM; i += 256) w3b[i] = (__bf16)W3[i];
        if (threadIdx.x < HM) wjc[threadIdx.x] = mpW1[threadIdx.x * 67 + 64];
    }
}

// ---------------------------------------------------------------------------
// Node projections (used only for step 0, h == 0):
//   hip[i][c] = b[i]*W1[c][65]
//   hjp[j][c] = b[j]*W1[c][66] + mp_b1[c]
// ---------------------------------------------------------------------------
__global__ __launch_bounds__(256) void node_proj0_kernel(
    const float* __restrict__ b,
    const float* __restrict__ mpW1, const float* __restrict__ mpb1,
    float* __restrict__ hipn, float* __restrict__ hjpn)
{
    int id = blockIdx.x * blockDim.x + threadIdx.x;   // 512*64
    if (id >= NN * HM) return;
    int i = id >> 6, c = id & 63;
    const float* w = mpW1 + c * 67;
    float bi = b[i];
    hipn[id] = bi * w[65];
    hjpn[id] = bi * w[66] + mpb1[c];
}

// ---------------------------------------------------------------------------
// Fused edge MLP + column-sum.  One block per destination j (512 blocks),
// 4 waves; wave w covers i in [w*128, w*128+128) in 8 groups of 16 edges.
// No per-group __syncthreads: the transpose buffer is per-wave; wave-lockstep
// + in-order DS + explicit lgkmcnt(0) give the ordering.
// ---------------------------------------------------------------------------
__global__ __launch_bounds__(256, 2) void edge_mlp_kernel(
    const float* __restrict__ hipn, const float* __restrict__ hjpn,
    const float* __restrict__ JT,
    const __bf16* __restrict__ w2b, const float* __restrict__ mpb2,
    const __bf16* __restrict__ w3b, const float* __restrict__ mpb3,
    const float* __restrict__ wjc,
    float* __restrict__ msg_sum)
{
    __shared__ __align__(16) float m2f[4][16][68];  // per-wave 16 edges x 64 ch (f32, +4 pad)
    __shared__ float msum[4][32];

    const int j    = blockIdx.x;
    const int lane = threadIdx.x & 63;
    const int wave = threadIdx.x >> 6;
    const int q    = lane >> 4;     // k-quad
    const int c    = lane & 15;     // A-row (edge) / C-col index

    // ---- per-wave preloads ----
    float hjp_r[16], wj_r[16];
    #pragma unroll
    for (int s = 0; s < 8; ++s) {
        int k0 = q * 8 + s;
        hjp_r[s]     = hjpn[j * 64 + k0];
        hjp_r[8 + s] = hjpn[j * 64 + k0 + 32];
        wj_r[s]      = wjc[k0];
        wj_r[8 + s]  = wjc[k0 + 32];
    }
    float b2v[4], b3v[2];
    #pragma unroll
    for (int t = 0; t < 4; ++t) b2v[t] = mpb2[t * 16 + c];
    #pragma unroll
    for (int t = 0; t < 2; ++t) b3v[t] = mpb3[t * 16 + c];

    // W2 as B-operand frags: element s -> W2[(t*16+c)][f*32+q*8+s]  (bf16 prepped)
    bf16x8 Bw2[2][4];
    #pragma unroll
    for (int f = 0; f < 2; ++f)
        #pragma unroll
        for (int t = 0; t < 4; ++t)
            Bw2[f][t] = *(const bf16x8*)(w2b + (t * 16 + c) * 64 + f * 32 + q * 8);
    bf16x8 Bw3[2][2];
    #pragma unroll
    for (int f = 0; f < 2; ++f)
        #pragma unroll
        for (int t = 0; t < 2; ++t)
            Bw3[f][t] = *(const bf16x8*)(w3b + (t * 16 + c) * 64 + f * 32 + q * 8);

    // J column for this wave's 128 rows, 2 values/lane
    float jA = JT[j * NN + wave * 128 + lane];
    float jB = JT[j * NN + wave * 128 + 64 + lane];

    float accf[2][4];
    #pragma unroll
    for (int t = 0; t < 2; ++t)
        #pragma unroll
        for (int r = 0; r < 4; ++r) accf[t][r] = 0.0f;

    const floatx4 zero4 = {0.f, 0.f, 0.f, 0.f};

    // prefetch group 0
    const float4* hp = (const float4*)(hipn + (wave * 128 + c) * 64);
    float4 nh0 = hp[q * 2];
    float4 nh1 = hp[q * 2 + 1];
    float4 nh2 = hp[q * 2 + 8];
    float4 nh3 = hp[q * 2 + 9];

    #pragma unroll
    for (int g = 0; g < 8; ++g) {
        float4 h0 = nh0, h1 = nh1, h2 = nh2, h3 = nh3;
        if (g < 7) {
            const float4* np = (const float4*)(hipn + (wave * 128 + (g + 1) * 16 + c) * 64);
            nh0 = np[q * 2];
            nh1 = np[q * 2 + 1];
            nh2 = np[q * 2 + 8];
            nh3 = np[q * 2 + 9];
        }
        float Jv = __shfl((g < 4) ? jA : jB, (g & 3) * 16 + c);

        float va[16];
        va[0]  = h0.x; va[1]  = h0.y; va[2]  = h0.z; va[3]  = h0.w;
        va[4]  = h1.x; va[5]  = h1.y; va[6]  = h1.z; va[7]  = h1.w;
        va[8]  = h2.x; va[9]  = h2.y; va[10] = h2.z; va[11] = h2.w;
        va[12] = h3.x; va[13] = h3.y; va[14] = h3.z; va[15] = h3.w;

        bf16x8 a0, a1;
        #pragma unroll
        for (int s = 0; s < 8; ++s) {
            float v0 = fmaf(Jv, wj_r[s],     va[s]     + hjp_r[s]);
            float v1 = fmaf(Jv, wj_r[8 + s], va[8 + s] + hjp_r[8 + s]);
            a0[s] = (__bf16)fmaxf(v0, 0.0f);
            a1[s] = (__bf16)fmaxf(v1, 0.0f);
        }

        // GEMM1: C layout: row=q*4+r (edge), col=t*16+c (ch)
        floatx4 c1[4];
        #pragma unroll
        for (int t = 0; t < 4; ++t) {
            c1[t] = __builtin_amdgcn_mfma_f32_16x16x32_bf16(a0, Bw2[0][t], zero4, 0, 0, 0);
            c1[t] = __builtin_amdgcn_mfma_f32_16x16x32_bf16(a1, Bw2[1][t], c1[t], 0, 0, 0);
        }

        // bias + relu -> per-wave LDS transpose buffer (f32, conflict-free)
        #pragma unroll
        for (int t = 0; t < 4; ++t)
            #pragma unroll
            for (int r = 0; r < 4; ++r)
                m2f[wave][q * 4 + r][t * 16 + c] = fmaxf(c1[t][r] + b2v[t], 0.0f);

        asm volatile("s_waitcnt lgkmcnt(0)" ::: "memory");  // RAW across lanes, same wave

        float4 ra0 = *(const float4*)&m2f[wave][c][q * 8];
        float4 ra1 = *(const float4*)&m2f[wave][c][q * 8 + 4];
        float4 ra2 = *(const float4*)&m2f[wave][c][q * 8 + 32];
        float4 ra3 = *(const float4*)&m2f[wave][c][q * 8 + 36];

        bf16x8 a2, a3;
        a2[0] = (__bf16)ra0.x; a2[1] = (__bf16)ra0.y; a2[2] = (__bf16)ra0.z; a2[3] = (__bf16)ra0.w;
        a2[4] = (__bf16)ra1.x; a2[5] = (__bf16)ra1.y; a2[6] = (__bf16)ra1.z; a2[7] = (__bf16)ra1.w;
        a3[0] = (__bf16)ra2.x; a3[1] = (__bf16)ra2.y; a3[2] = (__bf16)ra2.z; a3[3] = (__bf16)ra2.w;
        a3[4] = (__bf16)ra3.x; a3[5] = (__bf16)ra3.y; a3[6] = (__bf16)ra3.z; a3[7] = (__bf16)ra3.w;

        // GEMM2: msg_pre (16 edges x 32 ch)
        floatx4 c2[2];
        #pragma unroll
        for (int t = 0; t < 2; ++t) {
            c2[t] = __builtin_amdgcn_mfma_f32_16x16x32_bf16(a2, Bw3[0][t], zero4, 0, 0, 0);
            c2[t] = __builtin_amdgcn_mfma_f32_16x16x32_bf16(a3, Bw3[1][t], c2[t], 0, 0, 0);
        }
        #pragma unroll
        for (int t = 0; t < 2; ++t)
            #pragma unroll
            for (int r = 0; r < 4; ++r)
                accf[t][r] += fmaxf(c2[t][r] + b3v[t], 0.0f);

        asm volatile("s_waitcnt lgkmcnt(0)" ::: "memory");  // WAR before next group's writes
    }

    // column sums: each lane sums its 4 rows, then fold q-groups
    float s0 = accf[0][0] + accf[0][1] + accf[0][2] + accf[0][3];
    float s1 = accf[1][0] + accf[1][1] + accf[1][2] + accf[1][3];
    s0 += __shfl_xor(s0, 16); s0 += __shfl_xor(s0, 32);
    s1 += __shfl_xor(s1, 16); s1 += __shfl_xor(s1, 32);
    if (lane < 16) {
        msum[wave][c]      = s0;
        msum[wave][16 + c] = s1;
    }
    __syncthreads();
    if (threadIdx.x < 32) {
        float tot = msum[0][threadIdx.x] + msum[1][threadIdx.x] +
                    msum[2][threadIdx.x] + msum[3][threadIdx.x];
        msg_sum[j * 32 + threadIdx.x] = tot;
    }
}

// ---------------------------------------------------------------------------
// Fused GRU + (node projections | readout).  128 blocks x 256 = 4 nodes/block.
// ---------------------------------------------------------------------------
__global__ __launch_bounds__(256) void gru_proj_kernel(
    const float* __restrict__ h, const float* __restrict__ msg,
    const float* __restrict__ Wih, const float* __restrict__ Whh,
    const float* __restrict__ bih, const float* __restrict__ bhh,
    const float* __restrict__ mpW1, const float* __restrict__ mpb1,
    const float* __restrict__ b,
    float* __restrict__ hnew, float* __restrict__ hipn, float* __restrict__ hjpn,
    const float* __restrict__ rW1, const float* __restrict__ rb1,
    const float* __restrict__ rW2, const float* __restrict__ rb2,
    const float* __restrict__ rW3, const float* __restrict__ rb3,
    float* __restrict__ out,
    int hzero, int do_readout)
{
    __shared__ float hS[4][32];
    const int lane = threadIdx.x & 63;
    const int w    = threadIdx.x >> 6;
    const int n    = blockIdx.x * 4 + w;

    if (lane < 32) {
        const int d = lane;
        const float* hr = h + n * SD;
        const float* mr = msg + n * SD;
        float gi[3], gh[3];
        #pragma unroll
        for (int g = 0; g < 3; ++g) {
            const float* wi = Wih + (g * 32 + d) * 64;
            const float* wh = Whh + (g * 32 + d) * 32;
            float a  = bih[g * 32 + d];
            float bb = bhh[g * 32 + d];
            if (hzero) {
                #pragma unroll
                for (int k = 0; k < 32; ++k) a = fmaf(mr[k], wi[32 + k], a);
            } else {
                #pragma unroll
                for (int k = 0; k < 32; ++k) {
                    float hv = hr[k];
                    a  = fmaf(hv, wi[k], a);
                    a  = fmaf(mr[k], wi[32 + k], a);
                    bb = fmaf(hv, wh[k], bb);
                }
            }
            gi[g] = a; gh[g] = bb;
        }
        float r  = sigmoidf_(gi[0] + gh[0]);
        float z  = sigmoidf_(gi[1] + gh[1]);
        float ng = tanhf(gi[2] + r * gh[2]);
        float hprev = hzero ? 0.0f : hr[d];
        float hv = (1.0f - z) * ng + z * hprev;
        hS[w][d] = hv;
        hnew[n * SD + d] = hv;
    }
    __syncthreads();

    if (!do_readout) {
        // projections for (n, c=lane)
        const float* wr = mpW1 + lane * 67;
        float bi = b[n];
        float si = bi * wr[65];
        float sj = bi * wr[66] + mpb1[lane];
        #pragma unroll
        for (int d = 0; d < SD; ++d) {
            float hv = hS[w][d];
            si = fmaf(hv, wr[d], si);
            sj = fmaf(hv, wr[32 + d], sj);
        }
        hipn[n * HM + lane] = si;
        hjpn[n * HM + lane] = sj;
    } else {
        float y1 = rb1[lane];
        #pragma unroll
        for (int k = 0; k < 32; ++k) y1 = fmaf(hS[w][k], rW1[lane * 32 + k], y1);
        y1 = fmaxf(y1, 0.0f);
        float y2 = rb2[lane];
        #pragma unroll
        for (int k = 0; k < 64; ++k) y2 = fmaf(__shfl(y1, k), rW2[lane * 64 + k], y2);
        y2 = fmaxf(y2, 0.0f);
        float y3 = (lane < 2) ? rb3[lane] : 0.0f;
        #pragma unroll
        for (int k = 0; k < 64; ++k) {
            float v = __shfl(y2, k);
            if (lane < 2) y3 = fmaf(v, rW3[lane * 64 + k], y3);
        }
        if (lane < 2) out[n * 2 + lane] = sigmoidf_(y3);
    }
}

// ---------------------------------------------------------------------------
extern "C" void kernel_launch(void* const* d_in, const int* in_sizes, int n_in,
                              void* d_out, int out_size, void* d_ws, size_t ws_size,
                              hipStream_t stream)
{
    const float* J    = (const float*)d_in[0];
    const float* b    = (const float*)d_in[1];
    const float* mpW1 = (const float*)d_in[2];
    const float* mpb1 = (const float*)d_in[3];
    const float* mpW2 = (const float*)d_in[4];
    const float* mpb2 = (const float*)d_in[5];
    const float* mpW3 = (const float*)d_in[6];
    const float* mpb3 = (const float*)d_in[7];
    const float* Wih  = (const float*)d_in[8];
    const float* Whh  = (const float*)d_in[9];
    const float* bih  = (const float*)d_in[10];
    const float* bhh  = (const float*)d_in[11];
    const float* rW1  = (const float*)d_in[12];
    const float* rb1  = (const float*)d_in[13];
    const float* rW2  = (const float*)d_in[14];
    const float* rb2  = (const float*)d_in[15];
    const float* rW3  = (const float*)d_in[16];
    const float* rb3  = (const float*)d_in[17];

    float* ws   = (float*)d_ws;
    float* h0   = ws;                  // 512*32
    float* h1   = ws + 16384;          // 512*32
    float* hipA = ws + 32768;          // 512*64
    float* hjpA = ws + 65536;          // 512*64
    float* msg  = ws + 98304;          // 512*32
    float* JT   = ws + 114688;         // 512*512
    __bf16* w2b = (__bf16*)(ws + 376832);   // 64*64 bf16
    __bf16* w3b = (__bf16*)(ws + 378880);   // 32*64 bf16
    float* wjc  = ws + 379904;         // 64

    prep_kernel<<<256, 256, 0, stream>>>(J, JT, mpW2, mpW3, mpW1, w2b, w3b, wjc);
    node_proj0_kernel<<<128, 256, 0, stream>>>(b, mpW1, mpb1, hipA, hjpA);

    float* hc = h0;
    float* hn = h1;
    for (int t = 0; t < 5; ++t) {
        edge_mlp_kernel<<<NN, 256, 0, stream>>>(hipA, hjpA, JT, w2b, mpb2,
                                                w3b, mpb3, wjc, msg);
        gru_proj_kernel<<<128, 256, 0, stream>>>(hc, msg, Wih, Whh, bih, bhh,
                                                 mpW1, mpb1, b, hn, hipA, hjpA,
                                                 rW1, rb1, rW2, rb2, rW3, rb3,
                                                 (float*)d_out, t == 0, t == 4);
        float* tmp = hn; hn = hc; hc = tmp;
    }
}